// Round 7
// baseline (162.737 us; speedup 1.0000x reference)
//
#include <hip/hip_runtime.h>
#include <hip/hip_bf16.h>
#include <math.h>

// ---------------------------------------------------------------------------
// out[s] = (sum_i gate_i * x_i) @ Wm + (sum_i gate_i) * bm
// gate_i = softmax-with-eps over h_i = x_i.Wg + bg + pow*ln(w_i)
// index is SORTED -> segments are contiguous row ranges.
// ---------------------------------------------------------------------------

// K1: seg_start[s] = first row i with index[i] >= s ; seg_start[S] = N
__global__ __launch_bounds__(256) void k1_seg_offsets(const int* __restrict__ index,
                                                      int* __restrict__ seg_start,
                                                      int N, int S) {
    int i = blockIdx.x * blockDim.x + threadIdx.x;
    if (i >= N) return;
    int cur  = index[i];
    int prev = (i == 0) ? -1 : index[i - 1];
    for (int s = prev + 1; s <= cur; ++s) seg_start[s] = i;
    if (i == N - 1) {
        for (int s = cur + 1; s <= S; ++s) seg_start[s] = N;
    }
}

// K2: one wave per segment (oversubscribed grid -> HW self-balancing).
// Wave = 4 groups x 16 lanes; one row per group per step (float8/lane).
// ISSUE-ALL-THEN-DRAIN: all loads for up to 6 steps (24 rows) issued in one
// burst at wave start (clamped, unconditional); compute drains them in order
// behind ONE pipelined HBM latency. Tail loop (rare, >24-row segments) is
// load-then-compute. Defer-rescale softmax (THR=8); flash-combine per seg.

#define K2_ISSUE(k, Ak, Bk, Wk)                                              \
    {   int r  = rbg + 4 * (k);                                               \
        int rc = (r < last) ? r : last;                                       \
        const float* p_ = xb + (size_t)rc * 128;                              \
        Ak = *reinterpret_cast<const float4*>(p_);                            \
        Bk = *reinterpret_cast<const float4*>(p_ + 4);                        \
        Wk = wt[rc]; }

#define K2_COMP(k, Ak, Bk, Wk)                                                \
    {   bool v = (rbg + 4 * (k)) < end;                                       \
        float lw = fmaf(pw, __logf(Wk), bgv);                                 \
        float pp = Ak.x*wg0.x + Ak.y*wg0.y + Ak.z*wg0.z + Ak.w*wg0.w          \
                 + Bk.x*wg1.x + Bk.y*wg1.y + Bk.z*wg1.z + Bk.w*wg1.w;         \
        pp += __shfl_xor(pp, 1); pp += __shfl_xor(pp, 2);                     \
        pp += __shfl_xor(pp, 4); pp += __shfl_xor(pp, 8);                     \
        float h = v ? (pp + lw) : -1e30f;                                     \
        if (v && h > mg + 8.f) {                                              \
            float sc = __expf(mg - h);                                        \
            ssum *= sc;                                                       \
            _Pragma("unroll") for (int j = 0; j < 8; ++j) acc[j] *= sc;       \
            mg = h; }                                                         \
        float e = v ? __expf(h - mg) : 0.f;                                   \
        ssum += e;                                                            \
        acc[0] += e*Ak.x; acc[1] += e*Ak.y; acc[2] += e*Ak.z; acc[3] += e*Ak.w; \
        acc[4] += e*Bk.x; acc[5] += e*Bk.y; acc[6] += e*Bk.z; acc[7] += e*Bk.w; }

__global__ __launch_bounds__(256) void k2_seg_softmax_pool(
    const float* __restrict__ x, const float* __restrict__ wt,
    const float* __restrict__ Wg, const float* __restrict__ bg,
    const float* __restrict__ pw_, const int* __restrict__ seg_start,
    float* __restrict__ t, float* __restrict__ sgate, int S) {
    int gwid = (int)((blockIdx.x * 256 + threadIdx.x) >> 6);
    if (gwid >= S) return;
    int lane = threadIdx.x & 63;
    int grp  = lane >> 4;        // which row of the 4-row step
    int pos  = lane & 15;        // feature slice [8*pos, 8*pos+8)

    int start = seg_start[gwid], end = seg_start[gwid + 1];

    if (start >= end) {          // empty segment: exact zeros
        if (lane < 16) {
            float* tp = t + (size_t)gwid * 128 + pos * 8;
            *reinterpret_cast<float4*>(tp)     = make_float4(0.f, 0.f, 0.f, 0.f);
            *reinterpret_cast<float4*>(tp + 4) = make_float4(0.f, 0.f, 0.f, 0.f);
        }
        if (lane == 0) sgate[gwid] = 0.f;
        return;
    }

    float4 wg0 = *reinterpret_cast<const float4*>(Wg + pos * 8);
    float4 wg1 = *reinterpret_cast<const float4*>(Wg + pos * 8 + 4);
    float bgv = bg[0];
    float pw  = pw_[0];

    int nsteps = (end - start + 3) >> 2;
    int last   = end - 1;
    int rbg    = start + grp;                 // this group's row for step 0
    const float* xb = x + pos * 8;            // per-lane feature base

    // ---- burst-issue stages 0..5 (clamped; extra stages hit L1) ----
    float4 A0,B0,A1,B1,A2,B2,A3,B3,A4,B4,A5,B5;
    float  W0,W1,W2,W3,W4,W5;
    K2_ISSUE(0, A0, B0, W0);
    K2_ISSUE(1, A1, B1, W1);
    K2_ISSUE(2, A2, B2, W2);
    K2_ISSUE(3, A3, B3, W3);
    K2_ISSUE(4, A4, B4, W4);
    K2_ISSUE(5, A5, B5, W5);

    float mg = -INFINITY, ssum = 0.f;
    float acc[8];
    #pragma unroll
    for (int j = 0; j < 8; ++j) acc[j] = 0.f;

    // ---- drain (uniform branches; compute k waits only on stage k) ----
    K2_COMP(0, A0, B0, W0);
    if (nsteps > 1) {
        K2_COMP(1, A1, B1, W1);
        if (nsteps > 2) {
            K2_COMP(2, A2, B2, W2);
            if (nsteps > 3) {
                K2_COMP(3, A3, B3, W3);
                if (nsteps > 4) {
                    K2_COMP(4, A4, B4, W4);
                    if (nsteps > 5) {
                        K2_COMP(5, A5, B5, W5);
                        // rare tail: segments longer than 24 rows
                        for (int s = 6; s < nsteps; ++s) {
                            K2_ISSUE(s, A0, B0, W0);
                            K2_COMP(s, A0, B0, W0);
                        }
                    }
                }
            }
        }
    }

    // ---- flash-combine the 4 groups (xor 16, then 32) ----
    #pragma unroll
    for (int off = 16; off <= 32; off <<= 1) {
        float mo = __shfl_xor(mg, off);
        float so = __shfl_xor(ssum, off);
        float ao[8];
        #pragma unroll
        for (int j = 0; j < 8; ++j) ao[j] = __shfl_xor(acc[j], off);
        float mc = fmaxf(mg, mo);
        float c1 = (mg > -1e37f) ? __expf(mg - mc) : 0.f;   // -inf guard
        float c2 = (mo > -1e37f) ? __expf(mo - mc) : 0.f;
        ssum = ssum * c1 + so * c2;
        #pragma unroll
        for (int j = 0; j < 8; ++j) acc[j] = acc[j] * c1 + ao[j] * c2;
        mg = mc;
    }

    float inv = 1.f / (ssum + 1e-10f);
    if (lane < 16) {
        float* tp = t + (size_t)gwid * 128 + pos * 8;
        *reinterpret_cast<float4*>(tp) =
            make_float4(acc[0]*inv, acc[1]*inv, acc[2]*inv, acc[3]*inv);
        *reinterpret_cast<float4*>(tp + 4) =
            make_float4(acc[4]*inv, acc[5]*inv, acc[6]*inv, acc[7]*inv);
    }
    if (lane == 0) sgate[gwid] = ssum * inv;   // sum of normalized gates
}

// K3: out[row][:] = t[row][:] @ Wm + sgate[row] * bm
// 512 threads: 8 waves x 8 rows = 64 rows/block; Wm staged once in 64 KiB LDS.
__global__ __launch_bounds__(512) void k3_out_gemm(
    const float* __restrict__ t, const float* __restrict__ Wm,
    const float* __restrict__ bm, const float* __restrict__ sgate,
    float* __restrict__ out, int S) {
    __shared__ float2 lwm[128][64];   // lwm[k][l] = (Wm[k][l], Wm[k][l+64])
    int tid = threadIdx.x;
    for (int idx = tid; idx < 128 * 64; idx += 512) {
        int k = idx >> 6, l = idx & 63;
        lwm[k][l] = make_float2(Wm[k * 128 + l], Wm[k * 128 + 64 + l]);
    }
    __syncthreads();

    int wave = tid >> 6, lane = tid & 63;
    int row0 = (blockIdx.x * 8 + wave) * 8;       // 8 rows per wave
    if (row0 >= S) return;

    const float* tb = t + (size_t)__builtin_amdgcn_readfirstlane(row0) * 128;

    float accx[8], accy[8];
    #pragma unroll
    for (int r = 0; r < 8; ++r) { accx[r] = 0.f; accy[r] = 0.f; }

    for (int k = 0; k < 128; k += 4) {
        float2 w0 = lwm[k][lane],     w1 = lwm[k + 1][lane];
        float2 w2 = lwm[k + 2][lane], w3 = lwm[k + 3][lane];
        #pragma unroll
        for (int r = 0; r < 8; ++r) {
            const float* tr = tb + r * 128 + k;   // uniform -> s_load
            float t0 = tr[0], t1 = tr[1], t2 = tr[2], t3 = tr[3];
            accx[r] += t0 * w0.x; accy[r] += t0 * w0.y;
            accx[r] += t1 * w1.x; accy[r] += t1 * w1.y;
            accx[r] += t2 * w2.x; accy[r] += t2 * w2.y;
            accx[r] += t3 * w3.x; accy[r] += t3 * w3.y;
        }
    }

    float bmx = bm[lane], bmy = bm[lane + 64];
    #pragma unroll
    for (int r = 0; r < 8; ++r) {
        int row = row0 + r;
        if (row < S) {
            float sg = sgate[row];
            out[(size_t)row * 128 + lane]      = accx[r] + sg * bmx;
            out[(size_t)row * 128 + lane + 64] = accy[r] + sg * bmy;
        }
    }
}

extern "C" void kernel_launch(void* const* d_in, const int* in_sizes, int n_in,
                              void* d_out, int out_size, void* d_ws, size_t ws_size,
                              hipStream_t stream) {
    const float* x       = (const float*)d_in[0];
    const float* weights = (const float*)d_in[1];
    const float* Wg      = (const float*)d_in[2];
    const float* bg      = (const float*)d_in[3];
    const float* Wm      = (const float*)d_in[4];
    const float* bm      = (const float*)d_in[5];
    const float* pow_    = (const float*)d_in[6];
    const int*   index   = (const int*)d_in[7];
    float* out = (float*)d_out;

    int N = in_sizes[1];          // weights is [N,1]
    int S = out_size / 128;       // out is [S,128]

    // workspace layout
    char* ws = (char*)d_ws;
    int* seg_start = (int*)ws;                                  // (S+1) ints
    size_t off = (((size_t)(S + 1) * 4) + 255) & ~(size_t)255;
    float* sgate = (float*)(ws + off);                          // S floats
    off += (((size_t)S * 4) + 255) & ~(size_t)255;
    float* t = (float*)(ws + off);                              // (S+64)*128 floats (pad for K3 over-read)

    k1_seg_offsets<<<(N + 255) / 256, 256, 0, stream>>>(index, seg_start, N, S);
    k2_seg_softmax_pool<<<(S + 3) / 4, 256, 0, stream>>>(x, weights, Wg, bg, pow_,
                                                         seg_start, t, sgate, S);
    k3_out_gemm<<<(S + 63) / 64, 512, 0, stream>>>(t, Wm, bm, sgate, out, S);
}